// Round 1
// baseline (119.978 us; speedup 1.0000x reference)
//
#include <hip/hip_runtime.h>
#include <math.h>

#define BN_EPS 1e-5f

typedef _Float16 half2v __attribute__((ext_vector_type(2)));
typedef _Float16 half8v __attribute__((ext_vector_type(8)));
typedef __fp16 fp16x8 __attribute__((ext_vector_type(8)));
typedef float floatx4 __attribute__((ext_vector_type(4)));

__device__ __forceinline__ float fdot2(half2v a, half2v b, float c) {
    return __builtin_amdgcn_fdot2(a, b, c, false);
}
__device__ __forceinline__ half2v cvt2(float a, float b) {
    return __builtin_bit_cast(half2v, __builtin_amdgcn_cvt_pkrtz(a, b));
}
__device__ __forceinline__ floatx4 mfma16(half8v a, half8v b, floatx4 c) {
    return __builtin_amdgcn_mfma_f32_16x16x32_f16(
        __builtin_bit_cast(fp16x8, a), __builtin_bit_cast(fp16x8, b), c, 0, 0, 0);
}

// ---------------------------------------------------------------------------
// fused3 (MFMA): unchanged (verified). z=0: h16=relu(BN(x@W1^T+b1));
// z=1: A16=x@Wa^T+bs1; z=2: C16=x@Wb^T.
// ---------------------------------------------------------------------------
__global__ __launch_bounds__(256) void fused3_mfma(
    const float* __restrict__ x,
    const float* __restrict__ W1, const float* __restrict__ b1,
    const float* __restrict__ g, const float* __restrict__ be,
    const float* __restrict__ mu, const float* __restrict__ va,
    const float* __restrict__ Wa, const float* __restrict__ bs1,
    const float* __restrict__ Wb,
    _Float16* __restrict__ h16, _Float16* __restrict__ A16,
    _Float16* __restrict__ C16)
{
    __shared__ _Float16 Xs[64][264];
    __shared__ _Float16 Ws[32][264];

    const int t  = threadIdx.x;
    const int n0 = blockIdx.x * 32;
    const int m0 = blockIdx.y * 64;
    const int z  = blockIdx.z;
    const float* __restrict__ Wp = (z == 0) ? W1 : (z == 1 ? Wa : Wb);

    #pragma unroll
    for (int i = 0; i < 16; ++i) {
        const int cidx = t + i * 256;
        const int row = cidx >> 6;
        const int c4  = cidx & 63;
        const float4 v = *(const float4*)&x[(m0 + row) * 256 + c4 * 4];
        *(half2v*)&Xs[row][c4 * 4 + 0] = cvt2(v.x, v.y);
        *(half2v*)&Xs[row][c4 * 4 + 2] = cvt2(v.z, v.w);
    }
    #pragma unroll
    for (int i = 0; i < 8; ++i) {
        const int cidx = t + i * 256;
        const int row = cidx >> 6;
        const int c4  = cidx & 63;
        const float4 v = *(const float4*)&Wp[(n0 + row) * 256 + c4 * 4];
        *(half2v*)&Ws[row][c4 * 4 + 0] = cvt2(v.x, v.y);
        *(half2v*)&Ws[row][c4 * 4 + 2] = cvt2(v.z, v.w);
    }
    __syncthreads();

    const int wave = t >> 6;
    const int lane = t & 63;
    const int wy = wave >> 1, wx = wave & 1;
    const int lrow = lane & 15;
    const int quad = lane >> 4;
    const int kq = quad * 8;

    floatx4 acc[2] = {{0.f, 0.f, 0.f, 0.f}, {0.f, 0.f, 0.f, 0.f}};

    #pragma unroll
    for (int kc = 0; kc < 256; kc += 32) {
        const half8v a0 = *(const half8v*)&Xs[wy * 32 + lrow][kc + kq];
        const half8v a1 = *(const half8v*)&Xs[wy * 32 + 16 + lrow][kc + kq];
        const half8v b0 = *(const half8v*)&Ws[wx * 16 + lrow][kc + kq];
        acc[0] = mfma16(a0, b0, acc[0]);
        acc[1] = mfma16(a1, b0, acc[1]);
    }

    const int n = n0 + wx * 16 + lrow;
    float scale, off;
    if (z == 0) {
        const float s = g[n] * rsqrtf(va[n] + BN_EPS);
        scale = s;
        off = (b1[n] - mu[n]) * s + be[n];
    } else if (z == 1) {
        scale = 1.f;
        off = bs1[n];
    } else {
        scale = 1.f;
        off = 0.f;
    }
    _Float16* __restrict__ dst = (z == 0) ? h16 : (z == 1 ? A16 : C16);
    #pragma unroll
    for (int mi = 0; mi < 2; ++mi) {
        #pragma unroll
        for (int r = 0; r < 4; ++r) {
            const int m = m0 + wy * 32 + mi * 16 + quad * 4 + r;
            float v = acc[mi][r] * scale + off;
            if (z == 0) v = fmaxf(v, 0.f);
            dst[m * 512 + n] = (_Float16)v;
        }
    }
}

// ---------------------------------------------------------------------------
// tail2: bids 0..31 = head blocks (16 rows each): compute h2 tile in-block
//        via K-split MFMA (wave w owns K range [w*128,(w+1)*128)), LDS
//        partial-reduce, keep h2 row-slices in registers, then
//        scores = h2 @ W3^T + b3 and softmax. No h2 global round trip.
//        bids 32..559 = sim triangle tiles 16x16 (logic unchanged).
//        Head blocks first so they start early and overlap the sim tiles.
// ---------------------------------------------------------------------------
__global__ __launch_bounds__(256) void tail2_kernel(
    const _Float16* __restrict__ h16,
    const float* __restrict__ W2, const float* __restrict__ b2,
    const float* __restrict__ W3, const float* __restrict__ b3,
    const _Float16* __restrict__ A16, const _Float16* __restrict__ C16,
    const float* __restrict__ ws2, const float* __restrict__ bs2,
    float* __restrict__ out)
{
    __shared__ _Float16 RsQs[2][16][520];   // sim: Rs/Qs ; head: Xs / W2-chunk
    __shared__ half2v wsh[256];
    __shared__ float Tt[16][17];
    __shared__ float Hp[4][16][17];         // head: per-wave K-split partials

    const int bid = blockIdx.x;
    const int t   = threadIdx.x;

    if (bid < 32) {
        // ---- head: 16 rows of h2 + scores + softmax ----
        const int m0   = bid * 16;
        const int wave = t >> 6;
        const int lane = t & 63;
        const int lrow = lane & 15;
        const int quad = lane >> 4;
        const int m  = t >> 4;   // reduce/score role: row 0..15
        const int nn = t & 15;   // reduce/score role: col-within-chunk

        // stage h16 rows m0..m0+15 (f16 direct copy)
        #pragma unroll
        for (int i = 0; i < 4; ++i) {
            const int cidx = t + i * 256;
            const int row = cidx >> 6;
            const int c8  = cidx & 63;
            *(half8v*)&RsQs[0][row][c8 * 8] =
                *(const half8v*)&h16[(m0 + row) * 512 + c8 * 8];
        }

        float hr[16];   // this thread's h2[m0+m][16c+nn], c = 0..15
        #pragma unroll
        for (int c = 0; c < 16; ++c) {
            // stage W2 rows [16c, 16c+16) as f16
            #pragma unroll
            for (int i = 0; i < 4; ++i) {
                const int cidx = t + i * 256;
                const int row = cidx >> 6;
                const int c8  = cidx & 63;
                const float4 v0 = *(const float4*)&W2[(c * 16 + row) * 512 + c8 * 8];
                const float4 v1 = *(const float4*)&W2[(c * 16 + row) * 512 + c8 * 8 + 4];
                *(half2v*)&RsQs[1][row][c8 * 8 + 0] = cvt2(v0.x, v0.y);
                *(half2v*)&RsQs[1][row][c8 * 8 + 2] = cvt2(v0.z, v0.w);
                *(half2v*)&RsQs[1][row][c8 * 8 + 4] = cvt2(v1.x, v1.y);
                *(half2v*)&RsQs[1][row][c8 * 8 + 6] = cvt2(v1.z, v1.w);
            }
            __syncthreads();

            floatx4 acc = {0.f, 0.f, 0.f, 0.f};
            #pragma unroll
            for (int j = 0; j < 4; ++j) {
                const int kk = wave * 128 + j * 32 + quad * 8;
                const half8v a = *(const half8v*)&RsQs[0][lrow][kk];
                const half8v b = *(const half8v*)&RsQs[1][lrow][kk];
                acc = mfma16(a, b, acc);
            }
            #pragma unroll
            for (int r = 0; r < 4; ++r)
                Hp[wave][quad * 4 + r][lrow] = acc[r];
            __syncthreads();

            const float s = Hp[0][m][nn] + Hp[1][m][nn] +
                            Hp[2][m][nn] + Hp[3][m][nn] + b2[c * 16 + nn];
            hr[c] = fmaxf(s, 0.f);
        }

        // stage W3 (f32, 10x256) into the Xs region (free after last MFMA)
        float* W3f = (float*)&RsQs[0][0][0];
        #pragma unroll
        for (int i = 0; i < 10; ++i) W3f[t + i * 256] = W3[t + i * 256];
        __syncthreads();

        float p[10];
        #pragma unroll
        for (int q = 0; q < 10; ++q) {
            float a = 0.f;
            #pragma unroll
            for (int c = 0; c < 16; ++c)
                a = fmaf(hr[c], W3f[q * 256 + c * 16 + nn], a);
            p[q] = a;
        }
        // reduce over the 16 threads of each row-group (16-aligned lane groups)
        #pragma unroll
        for (int q = 0; q < 10; ++q) {
            #pragma unroll
            for (int off = 8; off > 0; off >>= 1)
                p[q] += __shfl_xor(p[q], off);
        }
        if (nn == 0) {
            const int r = m0 + m;
            float s[10], mx = -1e30f;
            #pragma unroll
            for (int q = 0; q < 10; ++q) { s[q] = p[q] + b3[q]; mx = fmaxf(mx, s[q]); }
            float e[10], sum = 0.f;
            #pragma unroll
            for (int q = 0; q < 10; ++q) { e[q] = __expf(s[q] - mx); sum += e[q]; }
            const float inv = 1.f / sum;
            #pragma unroll
            for (int q = 0; q < 10; ++q) {
                out[r * 10 + q] = e[q] * inv;
                out[5120 + r * 10 + q] = s[q];
            }
        }
        return;
    }

    // ---- sim triangle tile: b -> (it, jt) with it <= jt ----
    float* __restrict__ S = out + 10240;
    const int b = bid - 32;
    int jt = 0;
    {
        while ((jt + 1) * (jt + 2) / 2 <= b) ++jt;
    }
    const int it = b - jt * (jt + 1) / 2;
    const int r0 = it * 16, q0 = jt * 16;
    const bool diag = (it == jt);

    {
        half2v w;
        w.x = (_Float16)ws2[2 * t];
        w.y = (_Float16)ws2[2 * t + 1];
        wsh[t] = w;
    }
    #pragma unroll
    for (int i = 0; i < 4; ++i) {
        const int cidx = t + i * 256;
        const int row = cidx >> 6;
        const int c8  = cidx & 63;
        const float4 vr = *(const float4*)&A16[(r0 + row) * 512 + c8 * 8];
        const float4 vq = *(const float4*)&C16[(q0 + row) * 512 + c8 * 8];
        *(half8v*)&RsQs[0][row][c8 * 8] = __builtin_bit_cast(half8v, vr);
        *(half8v*)&RsQs[1][row][c8 * 8] = __builtin_bit_cast(half8v, vq);
    }
    __syncthreads();

    const int tx = t & 15, ty = t >> 4;
    const half2v* rp = (const half2v*)&RsQs[0][ty][0];
    const half2v* qp = (const half2v*)&RsQs[1][tx][0];
    const half2v z2 = {(_Float16)0, (_Float16)0};

    float a0 = 0.f;
    #pragma unroll 8
    for (int k2 = 0; k2 < 256; ++k2) {
        a0 = fdot2(__builtin_elementwise_max(rp[k2] + qp[k2], z2), wsh[k2], a0);
    }
    const float v = 1.f / (1.f + __expf(-(a0 + bs2[0])));

    Tt[ty][tx] = v;
    __syncthreads();

    if (diag) {
        const int r = r0 + ty, q = q0 + tx;
        const float o = (r < q) ? Tt[ty][tx] : (r > q ? Tt[tx][ty] : 0.f);
        S[r * 512 + q] = o;
    } else {
        S[(r0 + ty) * 512 + q0 + tx] = v;                 // direct
        S[(q0 + ty) * 512 + r0 + tx] = Tt[tx][ty];        // mirror (transposed)
    }
}

extern "C" void kernel_launch(void* const* d_in, const int* in_sizes, int n_in,
                              void* d_out, int out_size, void* d_ws, size_t ws_size,
                              hipStream_t stream)
{
    const float* x   = (const float*)d_in[0];
    const float* W1  = (const float*)d_in[1];
    const float* b1  = (const float*)d_in[2];
    const float* g   = (const float*)d_in[3];
    const float* be  = (const float*)d_in[4];
    const float* mu  = (const float*)d_in[5];
    const float* va  = (const float*)d_in[6];
    const float* W2  = (const float*)d_in[7];
    const float* b2  = (const float*)d_in[8];
    const float* W3  = (const float*)d_in[9];
    const float* b3  = (const float*)d_in[10];
    const float* Wa  = (const float*)d_in[11];
    const float* Wb  = (const float*)d_in[12];
    const float* bs1 = (const float*)d_in[13];
    const float* ws2 = (const float*)d_in[14];
    const float* bs2 = (const float*)d_in[15];

    float* out = (float*)d_out;
    _Float16* h16 = (_Float16*)d_ws;               // 512*512 f16
    _Float16* A16 = h16 + 512 * 512;               // 512*512 f16
    _Float16* C16 = A16 + 512 * 512;               // 512*512 f16

    fused3_mfma<<<dim3(16, 8, 3), 256, 0, stream>>>(x, W1, b1, g, be, mu, va,
                                                    Wa, bs1, Wb, h16, A16, C16);
    tail2_kernel<<<560, 256, 0, stream>>>(h16, W2, b2, W3, b3, A16, C16,
                                          ws2, bs2, out);
}

// Round 4
// 103.278 us; speedup vs baseline: 1.1617x; 1.1617x over previous
//
#include <hip/hip_runtime.h>
#include <math.h>

#define BN_EPS 1e-5f

typedef _Float16 half2v __attribute__((ext_vector_type(2)));
typedef _Float16 half4v __attribute__((ext_vector_type(4)));
typedef _Float16 half8v __attribute__((ext_vector_type(8)));
typedef __fp16 fp16x8 __attribute__((ext_vector_type(8)));
typedef float floatx4 __attribute__((ext_vector_type(4)));

__device__ __forceinline__ float fdot2(half2v a, half2v b, float c) {
    return __builtin_amdgcn_fdot2(a, b, c, false);
}
__device__ __forceinline__ half2v cvt2(float a, float b) {
    return __builtin_bit_cast(half2v, __builtin_amdgcn_cvt_pkrtz(a, b));
}
__device__ __forceinline__ floatx4 mfma16(half8v a, half8v b, floatx4 c) {
    return __builtin_amdgcn_mfma_f32_16x16x32_f16(
        __builtin_bit_cast(fp16x8, a), __builtin_bit_cast(fp16x8, b), c, 0, 0, 0);
}

// ---------------------------------------------------------------------------
// fused3 (MFMA): unchanged (verified). z=0: h16=relu(BN(x@W1^T+b1));
// z=1: A16=x@Wa^T+bs1; z=2: C16=x@Wb^T.
// ---------------------------------------------------------------------------
__global__ __launch_bounds__(256) void fused3_mfma(
    const float* __restrict__ x,
    const float* __restrict__ W1, const float* __restrict__ b1,
    const float* __restrict__ g, const float* __restrict__ be,
    const float* __restrict__ mu, const float* __restrict__ va,
    const float* __restrict__ Wa, const float* __restrict__ bs1,
    const float* __restrict__ Wb,
    _Float16* __restrict__ h16, _Float16* __restrict__ A16,
    _Float16* __restrict__ C16)
{
    __shared__ _Float16 Xs[64][264];
    __shared__ _Float16 Ws[32][264];

    const int t  = threadIdx.x;
    const int n0 = blockIdx.x * 32;
    const int m0 = blockIdx.y * 64;
    const int z  = blockIdx.z;
    const float* __restrict__ Wp = (z == 0) ? W1 : (z == 1 ? Wa : Wb);

    #pragma unroll
    for (int i = 0; i < 16; ++i) {
        const int cidx = t + i * 256;
        const int row = cidx >> 6;
        const int c4  = cidx & 63;
        const float4 v = *(const float4*)&x[(m0 + row) * 256 + c4 * 4];
        *(half2v*)&Xs[row][c4 * 4 + 0] = cvt2(v.x, v.y);
        *(half2v*)&Xs[row][c4 * 4 + 2] = cvt2(v.z, v.w);
    }
    #pragma unroll
    for (int i = 0; i < 8; ++i) {
        const int cidx = t + i * 256;
        const int row = cidx >> 6;
        const int c4  = cidx & 63;
        const float4 v = *(const float4*)&Wp[(n0 + row) * 256 + c4 * 4];
        *(half2v*)&Ws[row][c4 * 4 + 0] = cvt2(v.x, v.y);
        *(half2v*)&Ws[row][c4 * 4 + 2] = cvt2(v.z, v.w);
    }
    __syncthreads();

    const int wave = t >> 6;
    const int lane = t & 63;
    const int wy = wave >> 1, wx = wave & 1;
    const int lrow = lane & 15;
    const int quad = lane >> 4;
    const int kq = quad * 8;

    floatx4 acc[2] = {{0.f, 0.f, 0.f, 0.f}, {0.f, 0.f, 0.f, 0.f}};

    #pragma unroll
    for (int kc = 0; kc < 256; kc += 32) {
        const half8v a0 = *(const half8v*)&Xs[wy * 32 + lrow][kc + kq];
        const half8v a1 = *(const half8v*)&Xs[wy * 32 + 16 + lrow][kc + kq];
        const half8v b0 = *(const half8v*)&Ws[wx * 16 + lrow][kc + kq];
        acc[0] = mfma16(a0, b0, acc[0]);
        acc[1] = mfma16(a1, b0, acc[1]);
    }

    const int n = n0 + wx * 16 + lrow;
    float scale, off;
    if (z == 0) {
        const float s = g[n] * rsqrtf(va[n] + BN_EPS);
        scale = s;
        off = (b1[n] - mu[n]) * s + be[n];
    } else if (z == 1) {
        scale = 1.f;
        off = bs1[n];
    } else {
        scale = 1.f;
        off = 0.f;
    }
    _Float16* __restrict__ dst = (z == 0) ? h16 : (z == 1 ? A16 : C16);
    #pragma unroll
    for (int mi = 0; mi < 2; ++mi) {
        #pragma unroll
        for (int r = 0; r < 4; ++r) {
            const int m = m0 + wy * 32 + mi * 16 + quad * 4 + r;
            float v = acc[mi][r] * scale + off;
            if (z == 0) v = fmaxf(v, 0.f);
            dst[m * 512 + n] = (_Float16)v;
        }
    }
}

// ---------------------------------------------------------------------------
// h2 (MFMA) = relu(h16 @ W2^T + b2) fp32. M=512,N=256,K=512. (verified)
// ---------------------------------------------------------------------------
__global__ __launch_bounds__(256) void h2_mfma(
    const _Float16* __restrict__ h16, const float* __restrict__ W2,
    const float* __restrict__ b2, float* __restrict__ h2o)
{
    __shared__ _Float16 Xs[32][520];
    __shared__ _Float16 Ws[32][520];

    const int t  = threadIdx.x;
    const int n0 = blockIdx.x * 32;
    const int m0 = blockIdx.y * 32;

    #pragma unroll
    for (int i = 0; i < 8; ++i) {
        const int cidx = t + i * 256;
        const int row = cidx >> 6;
        const int c8  = cidx & 63;
        const float4 v = *(const float4*)&h16[(m0 + row) * 512 + c8 * 8];
        *(half8v*)&Xs[row][c8 * 8] = __builtin_bit_cast(half8v, v);
    }
    #pragma unroll
    for (int i = 0; i < 8; ++i) {
        const int cidx = t + i * 256;
        const int row = cidx >> 6;
        const int c8  = cidx & 63;
        const float4 v0 = *(const float4*)&W2[(n0 + row) * 512 + c8 * 8];
        const float4 v1 = *(const float4*)&W2[(n0 + row) * 512 + c8 * 8 + 4];
        *(half2v*)&Ws[row][c8 * 8 + 0] = cvt2(v0.x, v0.y);
        *(half2v*)&Ws[row][c8 * 8 + 2] = cvt2(v0.z, v0.w);
        *(half2v*)&Ws[row][c8 * 8 + 4] = cvt2(v1.x, v1.y);
        *(half2v*)&Ws[row][c8 * 8 + 6] = cvt2(v1.z, v1.w);
    }
    __syncthreads();

    const int wave = t >> 6;
    const int lane = t & 63;
    const int wy = wave >> 1, wx = wave & 1;
    const int lrow = lane & 15;
    const int quad = lane >> 4;
    const int kq = quad * 8;

    floatx4 acc = {0.f, 0.f, 0.f, 0.f};
    #pragma unroll
    for (int kc = 0; kc < 512; kc += 32) {
        const half8v a = *(const half8v*)&Xs[wy * 16 + lrow][kc + kq];
        const half8v b = *(const half8v*)&Ws[wx * 16 + lrow][kc + kq];
        acc = mfma16(a, b, acc);
    }

    const int n = n0 + wx * 16 + lrow;
    const float bb = b2[n];
    #pragma unroll
    for (int r = 0; r < 4; ++r) {
        const int m = m0 + wy * 16 + quad * 4 + r;
        h2o[m * 256 + n] = fmaxf(acc[r] + bb, 0.f);
    }
}

// ---------------------------------------------------------------------------
// tail3: bids 0..135 = sim triangle tiles 32x32, NO K-split. Each thread owns
//        4 outputs (row = wave*8+ly, cols lx+8c) with a full-K=512 sequential
//        fdot2 chain -- summation order identical to the verified 16x16
//        kernel. LDS reads amortized via half4v (ds_read_b64): 6 reads per
//        8 fdot2 vs 3 per 1 before. No LDS aliasing; separate T buffer.
//        bids 136..263 = head blocks (4 rows each), verified structure.
// ---------------------------------------------------------------------------
__global__ __launch_bounds__(256) void tail3_kernel(
    const float* __restrict__ h2, const float* __restrict__ W3,
    const float* __restrict__ b3,
    const _Float16* __restrict__ A16, const _Float16* __restrict__ C16,
    const float* __restrict__ ws2, const float* __restrict__ bs2,
    float* __restrict__ out)
{
    __shared__ __align__(16) _Float16 Rs[32][520];
    __shared__ __align__(16) _Float16 Qs[32][520];
    __shared__ __align__(16) _Float16 wshh[512];
    __shared__ float T[32][33];

    const int bid = blockIdx.x;
    const int t   = threadIdx.x;

    if (bid >= 136) {
        // ---- head: one wave per row, 4 rows/block (verified structure) ----
        const int lane = t & 63;
        const int r = (bid - 136) * 4 + (t >> 6);

        float p[10];
        #pragma unroll
        for (int q = 0; q < 10; ++q) p[q] = 0.f;
        #pragma unroll
        for (int kk = 0; kk < 4; ++kk) {
            const int k = lane + kk * 64;
            const float hv = h2[r * 256 + k];
            #pragma unroll
            for (int q = 0; q < 10; ++q)
                p[q] = fmaf(hv, W3[q * 256 + k], p[q]);
        }
        #pragma unroll
        for (int q = 0; q < 10; ++q) {
            #pragma unroll
            for (int off = 32; off > 0; off >>= 1)
                p[q] += __shfl_down(p[q], off);
        }
        if (lane == 0) {
            float s[10], m = -1e30f;
            #pragma unroll
            for (int q = 0; q < 10; ++q) { s[q] = p[q] + b3[q]; m = fmaxf(m, s[q]); }
            float e[10], sum = 0.f;
            #pragma unroll
            for (int q = 0; q < 10; ++q) { e[q] = __expf(s[q] - m); sum += e[q]; }
            const float inv = 1.f / sum;
            #pragma unroll
            for (int q = 0; q < 10; ++q) {
                out[r * 10 + q] = e[q] * inv;
                out[5120 + r * 10 + q] = s[q];
            }
        }
        return;
    }

    // ---- sim triangle tile 32x32: bid -> (it, jt) with it <= jt ----
    float* __restrict__ S = out + 10240;
    int jt = 0;
    {
        int b = bid;
        while ((jt + 1) * (jt + 2) / 2 <= b) ++jt;
    }
    const int it = bid - jt * (jt + 1) / 2;
    const int r0 = it * 32, q0 = jt * 32;
    const bool diag = (it == jt);

    // weights: 512 halfs
    {
        const float2 wv = *(const float2*)&ws2[2 * t];
        *(half2v*)&wshh[2 * t] = cvt2(wv.x, wv.y);
    }
    // stage 32 rows of A16 (Rs) and C16 (Qs): 2048 half8-chunks each
    #pragma unroll
    for (int i = 0; i < 8; ++i) {
        const int cidx = t + i * 256;
        const int row = cidx >> 6;
        const int c8  = cidx & 63;
        *(half8v*)&Rs[row][c8 * 8] =
            *(const half8v*)&A16[(r0 + row) * 512 + c8 * 8];
        *(half8v*)&Qs[row][c8 * 8] =
            *(const half8v*)&C16[(q0 + row) * 512 + c8 * 8];
    }
    __syncthreads();

    const int wave = t >> 6;
    const int lane = t & 63;
    const int ly = lane >> 3;       // 0..7
    const int lx = lane & 7;        // 0..7
    const int row = wave * 8 + ly;  // this thread's output row 0..31

    const half4v* ap  = (const half4v*)&Rs[row][0];
    const half4v* wp  = (const half4v*)&wshh[0];
    const half4v* q0p = (const half4v*)&Qs[lx +  0][0];
    const half4v* q1p = (const half4v*)&Qs[lx +  8][0];
    const half4v* q2p = (const half4v*)&Qs[lx + 16][0];
    const half4v* q3p = (const half4v*)&Qs[lx + 24][0];

    const half2v z2 = {(_Float16)0, (_Float16)0};
    float acc0 = 0.f, acc1 = 0.f, acc2 = 0.f, acc3 = 0.f;

    #pragma unroll 16
    for (int k4 = 0; k4 < 128; ++k4) {
        const half4v a4 = ap[k4];
        const half4v w4 = wp[k4];
        const half2v alo = __builtin_shufflevector(a4, a4, 0, 1);
        const half2v ahi = __builtin_shufflevector(a4, a4, 2, 3);
        const half2v wlo = __builtin_shufflevector(w4, w4, 0, 1);
        const half2v whi = __builtin_shufflevector(w4, w4, 2, 3);
        half4v q;
        q = q0p[k4];
        acc0 = fdot2(__builtin_elementwise_max(
                   alo + __builtin_shufflevector(q, q, 0, 1), z2), wlo, acc0);
        acc0 = fdot2(__builtin_elementwise_max(
                   ahi + __builtin_shufflevector(q, q, 2, 3), z2), whi, acc0);
        q = q1p[k4];
        acc1 = fdot2(__builtin_elementwise_max(
                   alo + __builtin_shufflevector(q, q, 0, 1), z2), wlo, acc1);
        acc1 = fdot2(__builtin_elementwise_max(
                   ahi + __builtin_shufflevector(q, q, 2, 3), z2), whi, acc1);
        q = q2p[k4];
        acc2 = fdot2(__builtin_elementwise_max(
                   alo + __builtin_shufflevector(q, q, 0, 1), z2), wlo, acc2);
        acc2 = fdot2(__builtin_elementwise_max(
                   ahi + __builtin_shufflevector(q, q, 2, 3), z2), whi, acc2);
        q = q3p[k4];
        acc3 = fdot2(__builtin_elementwise_max(
                   alo + __builtin_shufflevector(q, q, 0, 1), z2), wlo, acc3);
        acc3 = fdot2(__builtin_elementwise_max(
                   ahi + __builtin_shufflevector(q, q, 2, 3), z2), whi, acc3);
    }

    const float bb = bs2[0];
    T[row][lx +  0] = 1.f / (1.f + __expf(-(acc0 + bb)));
    T[row][lx +  8] = 1.f / (1.f + __expf(-(acc1 + bb)));
    T[row][lx + 16] = 1.f / (1.f + __expf(-(acc2 + bb)));
    T[row][lx + 24] = 1.f / (1.f + __expf(-(acc3 + bb)));
    __syncthreads();

    // global writes (+ transpose mirror), 16-lane coalesced runs
    const int ty = t >> 4, tx = t & 15;
    if (diag) {
        #pragma unroll
        for (int dy = 0; dy < 2; ++dy) {
            #pragma unroll
            for (int dx = 0; dx < 2; ++dx) {
                const int i = ty + dy * 16, jj = tx + dx * 16;
                const float o = (i < jj) ? T[i][jj]
                                         : (i > jj ? T[jj][i] : 0.f);
                S[(r0 + i) * 512 + q0 + jj] = o;
            }
        }
    } else {
        #pragma unroll
        for (int dy = 0; dy < 2; ++dy) {
            #pragma unroll
            for (int dx = 0; dx < 2; ++dx) {
                const int i = ty + dy * 16, jj = tx + dx * 16;
                S[(r0 + i) * 512 + q0 + jj] = T[i][jj];        // direct
                S[(q0 + i) * 512 + r0 + jj] = T[jj][i];        // mirror
            }
        }
    }
}

extern "C" void kernel_launch(void* const* d_in, const int* in_sizes, int n_in,
                              void* d_out, int out_size, void* d_ws, size_t ws_size,
                              hipStream_t stream)
{
    const float* x   = (const float*)d_in[0];
    const float* W1  = (const float*)d_in[1];
    const float* b1  = (const float*)d_in[2];
    const float* g   = (const float*)d_in[3];
    const float* be  = (const float*)d_in[4];
    const float* mu  = (const float*)d_in[5];
    const float* va  = (const float*)d_in[6];
    const float* W2  = (const float*)d_in[7];
    const float* b2  = (const float*)d_in[8];
    const float* W3  = (const float*)d_in[9];
    const float* b3  = (const float*)d_in[10];
    const float* Wa  = (const float*)d_in[11];
    const float* Wb  = (const float*)d_in[12];
    const float* bs1 = (const float*)d_in[13];
    const float* ws2 = (const float*)d_in[14];
    const float* bs2 = (const float*)d_in[15];

    float* out = (float*)d_out;
    _Float16* h16 = (_Float16*)d_ws;               // 512*512 f16
    float* h2 = (float*)(h16 + 512 * 512);         // 512*256 f32
    _Float16* A16 = (_Float16*)(h2 + 512 * 256);   // 512*512 f16
    _Float16* C16 = A16 + 512 * 512;               // 512*512 f16

    fused3_mfma<<<dim3(16, 8, 3), 256, 0, stream>>>(x, W1, b1, g, be, mu, va,
                                                    Wa, bs1, Wb, h16, A16, C16);
    h2_mfma<<<dim3(8, 16), 256, 0, stream>>>(h16, W2, b2, h2);
    tail3_kernel<<<264, 256, 0, stream>>>(h2, W3, b3, A16, C16, ws2, bs2, out);
}

// Round 5
// 100.496 us; speedup vs baseline: 1.1939x; 1.0277x over previous
//
#include <hip/hip_runtime.h>
#include <math.h>

#define BN_EPS 1e-5f

typedef _Float16 half2v __attribute__((ext_vector_type(2)));
typedef _Float16 half4v __attribute__((ext_vector_type(4)));
typedef _Float16 half8v __attribute__((ext_vector_type(8)));
typedef __fp16 fp16x8 __attribute__((ext_vector_type(8)));
typedef float floatx4 __attribute__((ext_vector_type(4)));

__device__ __forceinline__ float fdot2(half2v a, half2v b, float c) {
    return __builtin_amdgcn_fdot2(a, b, c, false);
}
__device__ __forceinline__ half2v cvt2(float a, float b) {
    return __builtin_bit_cast(half2v, __builtin_amdgcn_cvt_pkrtz(a, b));
}
__device__ __forceinline__ floatx4 mfma16(half8v a, half8v b, floatx4 c) {
    return __builtin_amdgcn_mfma_f32_16x16x32_f16(
        __builtin_bit_cast(fp16x8, a), __builtin_bit_cast(fp16x8, b), c, 0, 0, 0);
}

// ---------------------------------------------------------------------------
// fused3 (MFMA): unchanged (verified). z=0: h16=relu(BN(x@W1^T+b1));
// z=1: A16=x@Wa^T+bs1; z=2: C16=x@Wb^T.
// ---------------------------------------------------------------------------
__global__ __launch_bounds__(256) void fused3_mfma(
    const float* __restrict__ x,
    const float* __restrict__ W1, const float* __restrict__ b1,
    const float* __restrict__ g, const float* __restrict__ be,
    const float* __restrict__ mu, const float* __restrict__ va,
    const float* __restrict__ Wa, const float* __restrict__ bs1,
    const float* __restrict__ Wb,
    _Float16* __restrict__ h16, _Float16* __restrict__ A16,
    _Float16* __restrict__ C16)
{
    __shared__ _Float16 Xs[64][264];
    __shared__ _Float16 Ws[32][264];

    const int t  = threadIdx.x;
    const int n0 = blockIdx.x * 32;
    const int m0 = blockIdx.y * 64;
    const int z  = blockIdx.z;
    const float* __restrict__ Wp = (z == 0) ? W1 : (z == 1 ? Wa : Wb);

    #pragma unroll
    for (int i = 0; i < 16; ++i) {
        const int cidx = t + i * 256;
        const int row = cidx >> 6;
        const int c4  = cidx & 63;
        const float4 v = *(const float4*)&x[(m0 + row) * 256 + c4 * 4];
        *(half2v*)&Xs[row][c4 * 4 + 0] = cvt2(v.x, v.y);
        *(half2v*)&Xs[row][c4 * 4 + 2] = cvt2(v.z, v.w);
    }
    #pragma unroll
    for (int i = 0; i < 8; ++i) {
        const int cidx = t + i * 256;
        const int row = cidx >> 6;
        const int c4  = cidx & 63;
        const float4 v = *(const float4*)&Wp[(n0 + row) * 256 + c4 * 4];
        *(half2v*)&Ws[row][c4 * 4 + 0] = cvt2(v.x, v.y);
        *(half2v*)&Ws[row][c4 * 4 + 2] = cvt2(v.z, v.w);
    }
    __syncthreads();

    const int wave = t >> 6;
    const int lane = t & 63;
    const int wy = wave >> 1, wx = wave & 1;
    const int lrow = lane & 15;
    const int quad = lane >> 4;
    const int kq = quad * 8;

    floatx4 acc[2] = {{0.f, 0.f, 0.f, 0.f}, {0.f, 0.f, 0.f, 0.f}};

    #pragma unroll
    for (int kc = 0; kc < 256; kc += 32) {
        const half8v a0 = *(const half8v*)&Xs[wy * 32 + lrow][kc + kq];
        const half8v a1 = *(const half8v*)&Xs[wy * 32 + 16 + lrow][kc + kq];
        const half8v b0 = *(const half8v*)&Ws[wx * 16 + lrow][kc + kq];
        acc[0] = mfma16(a0, b0, acc[0]);
        acc[1] = mfma16(a1, b0, acc[1]);
    }

    const int n = n0 + wx * 16 + lrow;
    float scale, off;
    if (z == 0) {
        const float s = g[n] * rsqrtf(va[n] + BN_EPS);
        scale = s;
        off = (b1[n] - mu[n]) * s + be[n];
    } else if (z == 1) {
        scale = 1.f;
        off = bs1[n];
    } else {
        scale = 1.f;
        off = 0.f;
    }
    _Float16* __restrict__ dst = (z == 0) ? h16 : (z == 1 ? A16 : C16);
    #pragma unroll
    for (int mi = 0; mi < 2; ++mi) {
        #pragma unroll
        for (int r = 0; r < 4; ++r) {
            const int m = m0 + wy * 32 + mi * 16 + quad * 4 + r;
            float v = acc[mi][r] * scale + off;
            if (z == 0) v = fmaxf(v, 0.f);
            dst[m * 512 + n] = (_Float16)v;
        }
    }
}

// ---------------------------------------------------------------------------
// h2 (MFMA) = relu(h16 @ W2^T + b2) fp32. M=512,N=256,K=512. (verified)
// ---------------------------------------------------------------------------
__global__ __launch_bounds__(256) void h2_mfma(
    const _Float16* __restrict__ h16, const float* __restrict__ W2,
    const float* __restrict__ b2, float* __restrict__ h2o)
{
    __shared__ _Float16 Xs[32][520];
    __shared__ _Float16 Ws[32][520];

    const int t  = threadIdx.x;
    const int n0 = blockIdx.x * 32;
    const int m0 = blockIdx.y * 32;

    #pragma unroll
    for (int i = 0; i < 8; ++i) {
        const int cidx = t + i * 256;
        const int row = cidx >> 6;
        const int c8  = cidx & 63;
        const float4 v = *(const float4*)&h16[(m0 + row) * 512 + c8 * 8];
        *(half8v*)&Xs[row][c8 * 8] = __builtin_bit_cast(half8v, v);
    }
    #pragma unroll
    for (int i = 0; i < 8; ++i) {
        const int cidx = t + i * 256;
        const int row = cidx >> 6;
        const int c8  = cidx & 63;
        const float4 v0 = *(const float4*)&W2[(n0 + row) * 512 + c8 * 8];
        const float4 v1 = *(const float4*)&W2[(n0 + row) * 512 + c8 * 8 + 4];
        *(half2v*)&Ws[row][c8 * 8 + 0] = cvt2(v0.x, v0.y);
        *(half2v*)&Ws[row][c8 * 8 + 2] = cvt2(v0.z, v0.w);
        *(half2v*)&Ws[row][c8 * 8 + 4] = cvt2(v1.x, v1.y);
        *(half2v*)&Ws[row][c8 * 8 + 6] = cvt2(v1.z, v1.w);
    }
    __syncthreads();

    const int wave = t >> 6;
    const int lane = t & 63;
    const int wy = wave >> 1, wx = wave & 1;
    const int lrow = lane & 15;
    const int quad = lane >> 4;
    const int kq = quad * 8;

    floatx4 acc = {0.f, 0.f, 0.f, 0.f};
    #pragma unroll
    for (int kc = 0; kc < 512; kc += 32) {
        const half8v a = *(const half8v*)&Xs[wy * 16 + lrow][kc + kq];
        const half8v b = *(const half8v*)&Ws[wx * 16 + lrow][kc + kq];
        acc = mfma16(a, b, acc);
    }

    const int n = n0 + wx * 16 + lrow;
    const float bb = b2[n];
    #pragma unroll
    for (int r = 0; r < 4; ++r) {
        const int m = m0 + wy * 16 + quad * 4 + r;
        h2o[m * 256 + n] = fmaxf(acc[r] + bb, 0.f);
    }
}

// ---------------------------------------------------------------------------
// tail: verified 99us structure (656 blocks: 0..527 sim 16x16 triangle tiles,
// 528..655 head 4-rows). ONLY change vs baseline: sim inner loop reads
// Rs/Qs/wsh as half4v (ds_read_b64) instead of half2v (ds_read_b32) --
// 1.5 LDS instr per k-pair instead of 3, VALU and summation order identical.
// ---------------------------------------------------------------------------
__global__ __launch_bounds__(256) void tail_kernel(
    const float* __restrict__ h2, const float* __restrict__ W3,
    const float* __restrict__ b3,
    const _Float16* __restrict__ A16, const _Float16* __restrict__ C16,
    const float* __restrict__ ws2, const float* __restrict__ bs2,
    float* __restrict__ out)
{
    __shared__ __align__(16) _Float16 Rs[16][520];
    __shared__ __align__(16) _Float16 Qs[16][520];
    __shared__ __align__(16) _Float16 wsh[512];
    __shared__ float Tt[16][17];

    const int bid = blockIdx.x;
    const int t   = threadIdx.x;

    if (bid >= 528) {
        // ---- head: one wave per row, 4 rows/block ----
        const int lane = t & 63;
        const int r = (bid - 528) * 4 + (t >> 6);

        float p[10];
        #pragma unroll
        for (int q = 0; q < 10; ++q) p[q] = 0.f;
        #pragma unroll
        for (int kk = 0; kk < 4; ++kk) {
            const int k = lane + kk * 64;
            const float hv = h2[r * 256 + k];
            #pragma unroll
            for (int q = 0; q < 10; ++q)
                p[q] = fmaf(hv, W3[q * 256 + k], p[q]);
        }
        #pragma unroll
        for (int q = 0; q < 10; ++q) {
            #pragma unroll
            for (int off = 32; off > 0; off >>= 1)
                p[q] += __shfl_down(p[q], off);
        }
        if (lane == 0) {
            float s[10], m = -1e30f;
            #pragma unroll
            for (int q = 0; q < 10; ++q) { s[q] = p[q] + b3[q]; m = fmaxf(m, s[q]); }
            float e[10], sum = 0.f;
            #pragma unroll
            for (int q = 0; q < 10; ++q) { e[q] = __expf(s[q] - m); sum += e[q]; }
            const float inv = 1.f / sum;
            #pragma unroll
            for (int q = 0; q < 10; ++q) {
                out[r * 10 + q] = e[q] * inv;
                out[5120 + r * 10 + q] = s[q];
            }
        }
        return;
    }

    // ---- sim triangle tile: b -> (it, jt) with it <= jt ----
    float* __restrict__ S = out + 10240;
    int jt = 0;
    {
        int b = bid;
        while ((jt + 1) * (jt + 2) / 2 <= b) ++jt;
    }
    const int it = bid - jt * (jt + 1) / 2;
    const int r0 = it * 16, q0 = jt * 16;
    const bool diag = (it == jt);

    // weights: all 512 k as halfs
    {
        const float2 wv = *(const float2*)&ws2[2 * t];
        *(half2v*)&wsh[2 * t] = cvt2(wv.x, wv.y);
    }
    // Stage rows: A-rows r0.. (Rs) and C-rows q0.. (Qs), 16 rows x 64 chunks
    #pragma unroll
    for (int i = 0; i < 4; ++i) {
        const int cidx = t + i * 256;
        const int row = cidx >> 6;
        const int c8  = cidx & 63;
        const float4 vr = *(const float4*)&A16[(r0 + row) * 512 + c8 * 8];
        const float4 vq = *(const float4*)&C16[(q0 + row) * 512 + c8 * 8];
        *(half8v*)&Rs[row][c8 * 8] = __builtin_bit_cast(half8v, vr);
        *(half8v*)&Qs[row][c8 * 8] = __builtin_bit_cast(half8v, vq);
    }
    __syncthreads();

    const int tx = t & 15, ty = t >> 4;
    const half4v* rp = (const half4v*)&Rs[ty][0];
    const half4v* qp = (const half4v*)&Qs[tx][0];
    const half4v* wp = (const half4v*)&wsh[0];
    const half2v z2 = {(_Float16)0, (_Float16)0};

    float a0 = 0.f;
    #pragma unroll 8
    for (int k4 = 0; k4 < 128; ++k4) {
        const half4v a4 = rp[k4];
        const half4v q4 = qp[k4];
        const half4v w4 = wp[k4];
        const half2v alo = __builtin_shufflevector(a4, a4, 0, 1);
        const half2v ahi = __builtin_shufflevector(a4, a4, 2, 3);
        const half2v qlo = __builtin_shufflevector(q4, q4, 0, 1);
        const half2v qhi = __builtin_shufflevector(q4, q4, 2, 3);
        const half2v wlo = __builtin_shufflevector(w4, w4, 0, 1);
        const half2v whi = __builtin_shufflevector(w4, w4, 2, 3);
        a0 = fdot2(__builtin_elementwise_max(alo + qlo, z2), wlo, a0);
        a0 = fdot2(__builtin_elementwise_max(ahi + qhi, z2), whi, a0);
    }
    const float v = 1.f / (1.f + __expf(-(a0 + bs2[0])));

    Tt[ty][tx] = v;
    __syncthreads();

    if (diag) {
        const int r = r0 + ty, q = q0 + tx;
        const float o = (r < q) ? Tt[ty][tx] : (r > q ? Tt[tx][ty] : 0.f);
        S[r * 512 + q] = o;
    } else {
        S[(r0 + ty) * 512 + q0 + tx] = v;                 // direct
        S[(q0 + ty) * 512 + r0 + tx] = Tt[tx][ty];        // mirror (transposed)
    }
}

extern "C" void kernel_launch(void* const* d_in, const int* in_sizes, int n_in,
                              void* d_out, int out_size, void* d_ws, size_t ws_size,
                              hipStream_t stream)
{
    const float* x   = (const float*)d_in[0];
    const float* W1  = (const float*)d_in[1];
    const float* b1  = (const float*)d_in[2];
    const float* g   = (const float*)d_in[3];
    const float* be  = (const float*)d_in[4];
    const float* mu  = (const float*)d_in[5];
    const float* va  = (const float*)d_in[6];
    const float* W2  = (const float*)d_in[7];
    const float* b2  = (const float*)d_in[8];
    const float* W3  = (const float*)d_in[9];
    const float* b3  = (const float*)d_in[10];
    const float* Wa  = (const float*)d_in[11];
    const float* Wb  = (const float*)d_in[12];
    const float* bs1 = (const float*)d_in[13];
    const float* ws2 = (const float*)d_in[14];
    const float* bs2 = (const float*)d_in[15];

    float* out = (float*)d_out;
    _Float16* h16 = (_Float16*)d_ws;               // 512*512 f16
    float* h2 = (float*)(h16 + 512 * 512);         // 512*256 f32
    _Float16* A16 = (_Float16*)(h2 + 512 * 256);   // 512*512 f16
    _Float16* C16 = A16 + 512 * 512;               // 512*512 f16

    fused3_mfma<<<dim3(16, 8, 3), 256, 0, stream>>>(x, W1, b1, g, be, mu, va,
                                                    Wa, bs1, Wb, h16, A16, C16);
    h2_mfma<<<dim3(8, 16), 256, 0, stream>>>(h16, W2, b2, h2);
    tail_kernel<<<656, 256, 0, stream>>>(h2, W3, b3, A16, C16, ws2, bs2, out);
}